// Round 5
// baseline (231.441 us; speedup 1.0000x reference)
//
#include <hip/hip_runtime.h>
#include <hip/hip_bf16.h>

#define DEV __device__ __forceinline__

typedef __bf16 bf16;
typedef __bf16 bf16x4 __attribute__((ext_vector_type(4)));
typedef __bf16 bf16x8 __attribute__((ext_vector_type(8)));
typedef float f32x4 __attribute__((ext_vector_type(4)));

static constexpr int Bb = 4, Ll = 2048, Dd = 512, Ee = 8, Hh = 1024;
static constexpr int Mm = Bb * Ll;  // 8192 tokens
static constexpr int GKS = Ee * Hh; // 8192, G row stride

// ---------------- async global->LDS (16B per lane, wave-uniform LDS base) ---
DEV void gload_lds16(const void* g, void* l) {
  __builtin_amdgcn_global_load_lds(
      (const __attribute__((address_space(1))) unsigned int*)g,
      (__attribute__((address_space(3))) unsigned int*)l, 16, 0, 0);
}

// fast exact-enough gelu: tanh form, g = h - h/(exp(2y)+1)
DEV float gelu_fast(float h) {
  const float k = 0.7978845608028654f * 2.0f * 1.4426950408889634f;
  float h2 = h * h;
  float y = h * (k + (0.044715f * k) * h2);
  float t = exp2f(y);
  return h - h * __frcp_rn(t + 1.0f);
}

// ---------------- elementwise f32 -> bf16 -----------------------------------
__global__ void cvt_x_kernel(const float* __restrict__ in, bf16* __restrict__ out, int n4) {
  int i = blockIdx.x * blockDim.x + threadIdx.x;
  if (i < n4) {
    float4 v = ((const float4*)in)[i];
    bf16x4 o = {(bf16)v.x, (bf16)v.y, (bf16)v.z, (bf16)v.w};
    ((bf16x4*)out)[i] = o;
  }
}

// ---------------- tiled transpose + convert ---------------------------------
__global__ void transpose_cvt(const float* __restrict__ in, bf16* __restrict__ out,
                              int R, int C, size_t in_es, size_t out_es, int out_rs) {
  __shared__ float tile[64][65];
  const int e = blockIdx.z;
  const float* ip = in + (size_t)e * in_es;
  bf16* op = out + (size_t)e * out_es;
  const int r0 = blockIdx.y * 64, c0 = blockIdx.x * 64;
  const int tc = threadIdx.x & 63, tr = threadIdx.x >> 6;
#pragma unroll
  for (int i = 0; i < 16; ++i) {
    const int r = tr + i * 4;
    tile[r][tc] = ip[(size_t)(r0 + r) * C + c0 + tc];
  }
  __syncthreads();
  const int wr = threadIdx.x & 63, wc0 = threadIdx.x >> 6;
#pragma unroll
  for (int i = 0; i < 16; ++i) {
    const int c = wc0 + i * 4;
    op[(size_t)(c0 + c) * out_rs + r0 + wr] = (bf16)tile[wr][c];
  }
}

// ============ 256x256 8-phase deep-pipelined GEMM core (BK=64) ==============
// 512 threads = 8 waves (2M x 4N). LDS dbuf 128KB, XOR-swizzled.
// Counted vmcnt(8) keeps next tile's loads in flight across barriers (T4).
// MFMA operands swapped: acc[fi][fj][r]: m = wm*128+fi*16+(lane&15),
// n = wn*64+fj*16+(lane>>4)*4+r  (r-consecutive in n -> 8B-contiguous stores).
template <int ARS, int BRS>
DEV void gemm256_core(const bf16* __restrict__ Ag, const bf16* __restrict__ Bg,
                      int nt, f32x4 (&acc)[8][4], char* lds) {
  const int t = threadIdx.x;
  const int lane = t & 63;
  const int wid = t >> 6;
  const int wm = wid >> 2, wn = wid & 3;
  const int fr = lane & 15, fg = lane >> 4;
  const int srow = t >> 3;
  const int sseg = t & 7;

  auto stage = [&](int kt, int p) {
    char* As = lds + p * 65536;
    char* Bs = lds + p * 65536 + 32768;
#pragma unroll
    for (int i = 0; i < 4; ++i) {
      const int row = i * 64 + srow;
      const int q = sseg ^ (row & 7);
      gload_lds16(Ag + (size_t)row * ARS + kt * 64 + q * 8, As + i * 8192 + wid * 1024);
      gload_lds16(Bg + (size_t)row * BRS + kt * 64 + q * 8, Bs + i * 8192 + wid * 1024);
    }
  };

  stage(0, 0);
  for (int kt = 0; kt < nt; ++kt) {
    const int p = kt & 1;
    if (kt + 1 < nt) {
      stage(kt + 1, p ^ 1);
      asm volatile("s_waitcnt vmcnt(8)" ::: "memory");
    } else {
      asm volatile("s_waitcnt vmcnt(0)" ::: "memory");
    }
    __builtin_amdgcn_s_barrier();
    const char* As = lds + p * 65536;
    const char* Bs = lds + p * 65536 + 32768;
    bf16x8 bfrag[4][2];
#pragma unroll
    for (int q = 0; q < 4; ++q) {
      if (q == 0) {
#pragma unroll
        for (int fj = 0; fj < 4; ++fj)
#pragma unroll
          for (int kk = 0; kk < 2; ++kk) {
            const int row = wn * 64 + fj * 16 + fr;
            const int seg = (kk * 4 + fg) ^ (row & 7);
            bfrag[fj][kk] = *(const bf16x8*)(Bs + row * 128 + seg * 16);
          }
      }
      bf16x8 af[2][2];
#pragma unroll
      for (int fil = 0; fil < 2; ++fil)
#pragma unroll
        for (int kk = 0; kk < 2; ++kk) {
          const int row = wm * 128 + (q * 2 + fil) * 16 + fr;
          const int seg = (kk * 4 + fg) ^ (row & 7);
          af[fil][kk] = *(const bf16x8*)(As + row * 128 + seg * 16);
        }
      __builtin_amdgcn_s_barrier();
      asm volatile("s_waitcnt lgkmcnt(0)" ::: "memory");
      __builtin_amdgcn_sched_barrier(0);
      __builtin_amdgcn_s_setprio(1);
#pragma unroll
      for (int fil = 0; fil < 2; ++fil)
#pragma unroll
        for (int fj = 0; fj < 4; ++fj)
#pragma unroll
          for (int kk = 0; kk < 2; ++kk)
            acc[q * 2 + fil][fj] = __builtin_amdgcn_mfma_f32_16x16x32_bf16(
                bfrag[fj][kk], af[fil][kk], acc[q * 2 + fil][fj], 0, 0, 0);
      __builtin_amdgcn_s_setprio(0);
      __builtin_amdgcn_s_barrier();
    }
  }
}

// ---------------- stage 1 (256^2): g = w[m,e]*gelu(x@W1_e + b1_e) -----------
// Epilogue staged through LDS ([256][264] bf16, 135168B) for coalesced G writes.
__global__ __launch_bounds__(512, 2) void ffn_stage1_256(
    const bf16* __restrict__ xb, const bf16* __restrict__ w1t,
    const float* __restrict__ b1, const float* __restrict__ wts,
    bf16* __restrict__ G) {
  __shared__ __align__(16) char lds[135168];
  __shared__ float b1s[256];
  __shared__ float wls[256];
  const int mt = blockIdx.x;
  const int e = blockIdx.y >> 2, ht2 = blockIdx.y & 3;
  const int t = threadIdx.x;
  if (t < 256) b1s[t] = b1[e * Hh + ht2 * 256 + t];
  else wls[t - 256] = wts[((size_t)mt * 256 + (t - 256)) * Ee + e];

  f32x4 acc[8][4] = {};
  const bf16* Ag = xb + (size_t)mt * 256 * Dd;
  const bf16* Bg = w1t + ((size_t)e * Hh + (size_t)ht2 * 256) * Dd;
  gemm256_core<Dd, Dd>(Ag, Bg, Dd / 64, acc, lds);

  const int lane = t & 63, wid = t >> 6;
  const int wm = wid >> 2, wn = wid & 3;
  const int fr = lane & 15, fq = lane >> 4;
  float b1v[4][4];
#pragma unroll
  for (int fj = 0; fj < 4; ++fj)
#pragma unroll
    for (int r = 0; r < 4; ++r) b1v[fj][r] = b1s[wn * 64 + fj * 16 + fq * 4 + r];

  // fragments -> LDS tile [256 rows][264 elems] (row stride 528B)
  const float wgt0 = wls[wm * 128 + fr];  // depends on fi via +fi*16
#pragma unroll
  for (int fi = 0; fi < 8; ++fi) {
    const float wgt = wls[wm * 128 + fi * 16 + fr];
    char* rp = lds + (size_t)(wm * 128 + fi * 16 + fr) * 528 + wn * 128 + fq * 8;
#pragma unroll
    for (int fj = 0; fj < 4; ++fj) {
      bf16x4 o;
#pragma unroll
      for (int r = 0; r < 4; ++r) {
        float v = acc[fi][fj][r] + b1v[fj][r];
        o[r] = (bf16)(gelu_fast(v) * wgt);
      }
      *(bf16x4*)(rp + fj * 32) = o;
    }
  }
  (void)wgt0;
  __syncthreads();

  // coalesced write-out: 16 passes x (16 rows x 32 segs of 16B)
  bf16* gbase = G + ((size_t)mt * 256) * GKS + (size_t)e * Hh + ht2 * 256;
  const int seg = t & 31, rr = t >> 5;
#pragma unroll 4
  for (int p = 0; p < 16; ++p) {
    const int row = p * 16 + rr;
    bf16x8 v = *(const bf16x8*)(lds + (size_t)row * 528 + seg * 16);
    *(bf16x8*)(gbase + (size_t)row * GKS + seg * 8) = v;
  }
}

// ---------------- stage 2 (256^2) split-K partial ---------------------------
// Epilogue staged through LDS ([128][264] f32, two half-passes) for coalesced P.
__global__ __launch_bounds__(512, 2) void ffn_stage2_256(
    const bf16* __restrict__ G, const bf16* __restrict__ w2t,
    float* __restrict__ P, int kchunk) {
  __shared__ __align__(16) char lds[135168];
  const int mt = blockIdx.x, nt = blockIdx.y, s = blockIdx.z;
  f32x4 acc[8][4] = {};
  const bf16* Ag = G + (size_t)mt * 256 * GKS + (size_t)s * kchunk;
  const bf16* Bg = w2t + (size_t)nt * 256 * GKS + (size_t)s * kchunk;
  gemm256_core<GKS, GKS>(Ag, Bg, kchunk / 64, acc, lds);

  float* Pp = P + (size_t)s * Mm * Dd;
  const int t = threadIdx.x;
  const int lane = t & 63, wid = t >> 6;
  const int wm = wid >> 2, wn = wid & 3;
  const int fr = lane & 15, fq = lane >> 4;
  const int seg = t & 63, rr = t >> 6;

#pragma unroll
  for (int half = 0; half < 2; ++half) {
    __syncthreads();
    if (wm == half) {
#pragma unroll
      for (int fi = 0; fi < 8; ++fi) {
        char* rp = lds + (size_t)(fi * 16 + fr) * 1056 + wn * 256 + fq * 16;
#pragma unroll
        for (int fj = 0; fj < 4; ++fj) *(f32x4*)(rp + fj * 64) = acc[fi][fj];
      }
    }
    __syncthreads();
    float* pbase = Pp + ((size_t)mt * 256 + half * 128) * Dd + nt * 256;
#pragma unroll 4
    for (int it = 0; it < 16; ++it) {
      const int row = it * 8 + rr;
      f32x4 v = *(const f32x4*)(lds + (size_t)row * 1056 + seg * 16);
      *(f32x4*)(pbase + (size_t)row * Dd + seg * 4) = v;
    }
  }
}

// ---------------- reduce partials + bias ------------------------------------
__global__ __launch_bounds__(256) void reduce_bias(
    const float* __restrict__ P, const float* __restrict__ wts,
    const float* __restrict__ b2, float* __restrict__ out, int S) {
  const int n4 = Mm * Dd / 4;
  int i = blockIdx.x * 256 + threadIdx.x;
  if (i >= n4) return;
  const int m = i / (Dd / 4);
  const int d0 = (i % (Dd / 4)) * 4;
  float4 a = ((const float4*)P)[i];
  for (int s = 1; s < S; ++s) {
    float4 p = ((const float4*)P)[(size_t)s * n4 + i];
    a.x += p.x; a.y += p.y; a.z += p.z; a.w += p.w;
  }
  const float* wr = wts + (size_t)m * Ee;
#pragma unroll
  for (int e = 0; e < Ee; ++e) {
    const float w = wr[e];
    float4 b = *(const float4*)(b2 + e * Dd + d0);
    a.x += w * b.x; a.y += w * b.y; a.z += w * b.z; a.w += w * b.w;
  }
  ((float4*)out)[i] = a;
}

// ============ fallback: 128^2 m97-structure path (R3 proven) ================
template <int ARS, int BRS>
DEV void gemm_core(const bf16* __restrict__ Ag, const bf16* __restrict__ Bg,
                   int ksteps, f32x4 (&acc)[4][4], bf16* As, bf16* Bs) {
  const int t = threadIdx.x;
  const int lane = t & 63;
  const int w = t >> 6;
  const int srow = t >> 3;
  const int sseg = t & 7;
  const int wr = w >> 1, wc = w & 1;
  const int fr = lane & 15;
  const int fg = lane >> 4;
  for (int s = 0; s < ksteps; ++s) {
    __syncthreads();
#pragma unroll
    for (int i = 0; i < 4; ++i) {
      const int row = i * 32 + srow;
      const int q = sseg ^ (row & 7);
      gload_lds16(Ag + (size_t)row * ARS + s * 64 + q * 8,
                  (char*)As + i * 4096 + w * 1024);
      gload_lds16(Bg + (size_t)row * BRS + s * 64 + q * 8,
                  (char*)Bs + i * 4096 + w * 1024);
    }
    __syncthreads();
#pragma unroll
    for (int kk = 0; kk < 2; ++kk) {
      bf16x8 af[4], bfr[4];
#pragma unroll
      for (int mi = 0; mi < 4; ++mi) {
        const int row = wr * 64 + mi * 16 + fr;
        const int q = (kk * 4 + fg) ^ (row & 7);
        af[mi] = *(const bf16x8*)((const char*)As + row * 128 + q * 16);
      }
#pragma unroll
      for (int ni = 0; ni < 4; ++ni) {
        const int row = wc * 64 + ni * 16 + fr;
        const int q = (kk * 4 + fg) ^ (row & 7);
        bfr[ni] = *(const bf16x8*)((const char*)Bs + row * 128 + q * 16);
      }
#pragma unroll
      for (int mi = 0; mi < 4; ++mi)
#pragma unroll
        for (int ni = 0; ni < 4; ++ni)
          acc[mi][ni] = __builtin_amdgcn_mfma_f32_16x16x32_bf16(
              af[mi], bfr[ni], acc[mi][ni], 0, 0, 0);
    }
  }
}

__global__ __launch_bounds__(256) void ffn_stage1_t(
    const bf16* __restrict__ xb, const bf16* __restrict__ w1t,
    const float* __restrict__ b1, const float* __restrict__ wts,
    bf16* __restrict__ G) {
  __shared__ __align__(16) bf16 As[128 * 64];
  __shared__ __align__(16) bf16 Bs[128 * 64];
  __shared__ float b1s[128];
  __shared__ float wls[128];
  const int mt = blockIdx.x, ht = blockIdx.y, e = blockIdx.z;
  const int t = threadIdx.x;
  if (t < 128) b1s[t] = b1[e * Hh + ht * 128 + t];
  else wls[t - 128] = wts[((size_t)mt * 128 + (t - 128)) * Ee + e];
  f32x4 acc[4][4] = {};
  const bf16* Ag = xb + (size_t)mt * 128 * Dd;
  const bf16* Bg = w1t + ((size_t)e * Hh + (size_t)ht * 128) * Dd;
  gemm_core<Dd, Dd>(Ag, Bg, Dd / 64, acc, As, Bs);
  const int lane = t & 63, w = t >> 6;
  const int wr = w >> 1, wc = w & 1, fr = lane & 15, fq = lane >> 4;
  float bcol[4];
#pragma unroll
  for (int ni = 0; ni < 4; ++ni) bcol[ni] = b1s[wc * 64 + ni * 16 + fr];
  bf16* gp = G + ((size_t)mt * 128 + wr * 64 + fq * 4) * GKS
               + (size_t)e * Hh + ht * 128 + wc * 64 + fr;
#pragma unroll
  for (int mi = 0; mi < 4; ++mi)
#pragma unroll
    for (int r = 0; r < 4; ++r) {
      const float wgt = wls[wr * 64 + mi * 16 + fq * 4 + r];
#pragma unroll
      for (int ni = 0; ni < 4; ++ni) {
        float v = acc[mi][ni][r] + bcol[ni];
        gp[(size_t)(mi * 16 + r) * GKS + ni * 16] = (bf16)(gelu_fast(v) * wgt);
      }
    }
}

__global__ __launch_bounds__(256) void ffn_stage2_partial(
    const bf16* __restrict__ G, const bf16* __restrict__ w2t,
    float* __restrict__ P, int kchunk) {
  __shared__ __align__(16) bf16 As[128 * 64];
  __shared__ __align__(16) bf16 Bs[128 * 64];
  const int mt = blockIdx.x, nt = blockIdx.y, s = blockIdx.z;
  f32x4 acc[4][4] = {};
  const bf16* Ag = G + (size_t)mt * 128 * GKS + (size_t)s * kchunk;
  const bf16* Bg = w2t + (size_t)nt * 128 * GKS + (size_t)s * kchunk;
  gemm_core<GKS, GKS>(Ag, Bg, kchunk / 64, acc, As, Bs);
  float* Pp = P + (size_t)s * Mm * Dd;
  const int t = threadIdx.x;
  const int lane = t & 63, w = t >> 6;
  const int wr = w >> 1, wc = w & 1, fr = lane & 15, fq = lane >> 4;
#pragma unroll
  for (int mi = 0; mi < 4; ++mi)
#pragma unroll
    for (int r = 0; r < 4; ++r) {
      const size_t m = (size_t)mt * 128 + wr * 64 + mi * 16 + fq * 4 + r;
#pragma unroll
      for (int ni = 0; ni < 4; ++ni) {
        const int d = nt * 128 + wc * 64 + ni * 16 + fr;
        Pp[m * Dd + d] = acc[mi][ni][r];
      }
    }
}

// ---------------- launch ----------------------------------------------------
extern "C" void kernel_launch(void* const* d_in, const int* in_sizes, int n_in,
                              void* d_out, int out_size, void* d_ws, size_t ws_size,
                              hipStream_t stream) {
  const float* x   = (const float*)d_in[0];
  const float* wts = (const float*)d_in[1];
  const float* w1  = (const float*)d_in[2];
  const float* b1  = (const float*)d_in[3];
  const float* w2  = (const float*)d_in[4];
  const float* b2  = (const float*)d_in[5];
  float* out = (float*)d_out;

  char* ws = (char*)d_ws;
  size_t off = 0;
  bf16* xb  = (bf16*)(ws + off); off += (size_t)Mm * Dd * 2;
  bf16* w1t = (bf16*)(ws + off); off += (size_t)Ee * Hh * Dd * 2;
  bf16* w2t = (bf16*)(ws + off); off += (size_t)Dd * Ee * Hh * 2;

  const size_t gfull = (size_t)Mm * Ee * Hh * 2;  // 134 MB
  const size_t psz   = (size_t)Mm * Dd * 4;       // 16.8 MB

  cvt_x_kernel<<<(Mm * Dd / 4 + 255) / 256, 256, 0, stream>>>(x, xb, Mm * Dd / 4);
  transpose_cvt<<<dim3(Hh / 64, Dd / 64, Ee), 256, 0, stream>>>(
      w1, w1t, Dd, Hh, (size_t)Dd * Hh, (size_t)Hh * Dd, Dd);
  transpose_cvt<<<dim3(Dd / 64, Hh / 64, Ee), 256, 0, stream>>>(
      w2, w2t, Hh, Dd, (size_t)Hh * Dd, (size_t)Hh, Ee * Hh);

  if (ws_size >= off + gfull + 4 * psz) {
    // main path: 256^2 8-phase kernels + LDS-coalesced epilogues, split-K S=4
    bf16* G = (bf16*)(ws + off);
    float* P = (float*)(ws + off + gfull);
    ffn_stage1_256<<<dim3(Mm / 256, (Ee * Hh) / 256), 512, 0, stream>>>(
        xb, w1t, b1, wts, G);
    ffn_stage2_256<<<dim3(Mm / 256, Dd / 256, 4), 512, 0, stream>>>(
        G, w2t, P, GKS / 4);
    reduce_bias<<<(Mm * Dd / 4 + 255) / 256, 256, 0, stream>>>(P, wts, b2, out, 4);
  } else if (ws_size >= off + gfull + 2 * psz) {
    // fallback: 128^2 split-K S=2 (R3 proven)
    bf16* G = (bf16*)(ws + off);
    float* P = (float*)(ws + off + gfull);
    ffn_stage1_t<<<dim3(Mm / 128, Hh / 128, Ee), 256, 0, stream>>>(
        xb, w1t, b1, wts, G);
    ffn_stage2_partial<<<dim3(Mm / 128, Dd / 128, 2), 256, 0, stream>>>(
        G, w2t, P, GKS / 2);
    reduce_bias<<<(Mm * Dd / 4 + 255) / 256, 256, 0, stream>>>(P, wts, b2, out, 2);
  }
}

// Round 7
// 222.177 us; speedup vs baseline: 1.0417x; 1.0417x over previous
//
#include <hip/hip_runtime.h>
#include <hip/hip_bf16.h>

#define DEV __device__ __forceinline__

typedef __bf16 bf16;
typedef __bf16 bf16x4 __attribute__((ext_vector_type(4)));
typedef __bf16 bf16x8 __attribute__((ext_vector_type(8)));
typedef float f32x4 __attribute__((ext_vector_type(4)));

static constexpr int Bb = 4, Ll = 2048, Dd = 512, Ee = 8, Hh = 1024;
static constexpr int Mm = Bb * Ll;  // 8192 tokens
static constexpr int GKS = Ee * Hh; // 8192, G row stride

// ---------------- async global->LDS (16B per lane, wave-uniform LDS base) ---
DEV void gload_lds16(const void* g, void* l) {
  __builtin_amdgcn_global_load_lds(
      (const __attribute__((address_space(1))) unsigned int*)g,
      (__attribute__((address_space(3))) unsigned int*)l, 16, 0, 0);
}

// fast exact-enough gelu: tanh form, g = h - h/(exp(2y)+1)
DEV float gelu_fast(float h) {
  const float k = 0.7978845608028654f * 2.0f * 1.4426950408889634f;
  float h2 = h * h;
  float y = h * (k + (0.044715f * k) * h2);
  float t = exp2f(y);
  return h - h * __frcp_rn(t + 1.0f);
}

// ---------------- elementwise f32 -> bf16 -----------------------------------
__global__ void cvt_x_kernel(const float* __restrict__ in, bf16* __restrict__ out, int n4) {
  int i = blockIdx.x * blockDim.x + threadIdx.x;
  if (i < n4) {
    float4 v = ((const float4*)in)[i];
    bf16x4 o = {(bf16)v.x, (bf16)v.y, (bf16)v.z, (bf16)v.w};
    ((bf16x4*)out)[i] = o;
  }
}

// ---------------- tiled transpose + convert ---------------------------------
__global__ void transpose_cvt(const float* __restrict__ in, bf16* __restrict__ out,
                              int R, int C, size_t in_es, size_t out_es, int out_rs) {
  __shared__ float tile[64][65];
  const int e = blockIdx.z;
  const float* ip = in + (size_t)e * in_es;
  bf16* op = out + (size_t)e * out_es;
  const int r0 = blockIdx.y * 64, c0 = blockIdx.x * 64;
  const int tc = threadIdx.x & 63, tr = threadIdx.x >> 6;
#pragma unroll
  for (int i = 0; i < 16; ++i) {
    const int r = tr + i * 4;
    tile[r][tc] = ip[(size_t)(r0 + r) * C + c0 + tc];
  }
  __syncthreads();
  const int wr = threadIdx.x & 63, wc0 = threadIdx.x >> 6;
#pragma unroll
  for (int i = 0; i < 16; ++i) {
    const int c = wc0 + i * 4;
    op[(size_t)(c0 + c) * out_rs + r0 + wr] = (bf16)tile[wr][c];
  }
}

// ---------------- stage 1: persistent over ht2 ------------------------------
// Grid (32 mt, 8 e) = 256 blocks = 1 round/CU. Flat 32-iter pipeline:
// it = ht2*8 + kt, one counted-vmcnt dbuf pipeline across all 4 ht2 tiles.
// Per-ht2 epilogue (direct stores) overlaps next ht2's staging.
__global__ __launch_bounds__(512, 2) void ffn_stage1_256(
    const bf16* __restrict__ xb, const bf16* __restrict__ w1t,
    const float* __restrict__ b1, const float* __restrict__ wts,
    bf16* __restrict__ G) {
  __shared__ __align__(16) char lds[131072];
  __shared__ float b1s[1024];
  __shared__ float wls[256];
  const int mt = blockIdx.x, e = blockIdx.y;
  const int t = threadIdx.x;
  b1s[t] = b1[e * Hh + t];
  b1s[512 + t] = b1[e * Hh + 512 + t];
  if (t < 256) wls[t] = wts[((size_t)mt * 256 + t) * Ee + e];

  const int lane = t & 63;
  const int wid = t >> 6;
  const int wm = wid >> 2, wn = wid & 3;
  const int fr = lane & 15, fg = lane >> 4, fq = lane >> 4;
  const int srow = t >> 3;
  const int sseg = t & 7;

  const bf16* Ag = xb + (size_t)mt * 256 * Dd;
  const bf16* Bg0 = w1t + (size_t)e * Hh * Dd;

  auto stage = [&](int it, int p) {
    const int ht2n = it >> 3, ktn = it & 7;
    const bf16* Bg = Bg0 + (size_t)ht2n * 256 * Dd;
    char* As = lds + p * 65536;
    char* Bs = lds + p * 65536 + 32768;
#pragma unroll
    for (int i = 0; i < 4; ++i) {
      const int row = i * 64 + srow;
      const int q = sseg ^ (row & 7);
      gload_lds16(Ag + (size_t)row * Dd + ktn * 64 + q * 8, As + i * 8192 + wid * 1024);
      gload_lds16(Bg + (size_t)row * Dd + ktn * 64 + q * 8, Bs + i * 8192 + wid * 1024);
    }
  };

  f32x4 acc[8][4] = {};
  stage(0, 0);
  for (int it = 0; it < 32; ++it) {
    const int p = it & 1;
    if (it + 1 < 32) {
      stage(it + 1, p ^ 1);
      asm volatile("s_waitcnt vmcnt(8)" ::: "memory");
    } else {
      asm volatile("s_waitcnt vmcnt(0)" ::: "memory");
    }
    __builtin_amdgcn_s_barrier();
    const char* As = lds + p * 65536;
    const char* Bs = lds + p * 65536 + 32768;
    bf16x8 bfrag[4][2];
#pragma unroll
    for (int q = 0; q < 4; ++q) {
      if (q == 0) {
#pragma unroll
        for (int fj = 0; fj < 4; ++fj)
#pragma unroll
          for (int kk = 0; kk < 2; ++kk) {
            const int row = wn * 64 + fj * 16 + fr;
            const int seg = (kk * 4 + fg) ^ (row & 7);
            bfrag[fj][kk] = *(const bf16x8*)(Bs + row * 128 + seg * 16);
          }
      }
      bf16x8 af[2][2];
#pragma unroll
      for (int fil = 0; fil < 2; ++fil)
#pragma unroll
        for (int kk = 0; kk < 2; ++kk) {
          const int row = wm * 128 + (q * 2 + fil) * 16 + fr;
          const int seg = (kk * 4 + fg) ^ (row & 7);
          af[fil][kk] = *(const bf16x8*)(As + row * 128 + seg * 16);
        }
      __builtin_amdgcn_s_barrier();
      asm volatile("s_waitcnt lgkmcnt(0)" ::: "memory");
      __builtin_amdgcn_sched_barrier(0);
      __builtin_amdgcn_s_setprio(1);
#pragma unroll
      for (int fil = 0; fil < 2; ++fil)
#pragma unroll
        for (int fj = 0; fj < 4; ++fj)
#pragma unroll
          for (int kk = 0; kk < 2; ++kk)
            acc[q * 2 + fil][fj] = __builtin_amdgcn_mfma_f32_16x16x32_bf16(
                bfrag[fj][kk], af[fil][kk], acc[q * 2 + fil][fj], 0, 0, 0);
      __builtin_amdgcn_s_setprio(0);
      __builtin_amdgcn_s_barrier();
    }
    if ((it & 7) == 7) {
      const int ht2 = it >> 3;
      float b1v[4][4];
#pragma unroll
      for (int fj = 0; fj < 4; ++fj)
#pragma unroll
        for (int r = 0; r < 4; ++r)
          b1v[fj][r] = b1s[ht2 * 256 + wn * 64 + fj * 16 + fq * 4 + r];
#pragma unroll
      for (int fi = 0; fi < 8; ++fi) {
        const int m = mt * 256 + wm * 128 + fi * 16 + fr;
        const float wgt = wls[wm * 128 + fi * 16 + fr];
        bf16* gp = G + (size_t)m * GKS + e * Hh + ht2 * 256 + wn * 64 + fq * 4;
#pragma unroll
        for (int fj = 0; fj < 4; ++fj) {
          bf16x4 o;
#pragma unroll
          for (int r = 0; r < 4; ++r) {
            float v = acc[fi][fj][r] + b1v[fj][r];
            o[r] = (bf16)(gelu_fast(v) * wgt);
          }
          *(bf16x4*)(gp + fj * 16) = o;
        }
#pragma unroll
        for (int fj = 0; fj < 4; ++fj) acc[fi][fj] = (f32x4){0.f, 0.f, 0.f, 0.f};
      }
    }
  }
}

// ---------------- stage 2 (256^2) split-K partial (R4 proven) ---------------
__global__ __launch_bounds__(512, 2) void ffn_stage2_256(
    const bf16* __restrict__ G, const bf16* __restrict__ w2t,
    float* __restrict__ P, int kchunk) {
  __shared__ __align__(16) char lds[131072];
  const int mt = blockIdx.x, nt = blockIdx.y, s = blockIdx.z;
  const int t = threadIdx.x;
  const int lane = t & 63;
  const int wid = t >> 6;
  const int wm = wid >> 2, wn = wid & 3;
  const int fr = lane & 15, fg = lane >> 4;
  const int srow = t >> 3;
  const int sseg = t & 7;

  const bf16* Ag = G + (size_t)mt * 256 * GKS + (size_t)s * kchunk;
  const bf16* Bg = w2t + (size_t)nt * 256 * GKS + (size_t)s * kchunk;

  auto stage = [&](int kt, int p) {
    char* As = lds + p * 65536;
    char* Bs = lds + p * 65536 + 32768;
#pragma unroll
    for (int i = 0; i < 4; ++i) {
      const int row = i * 64 + srow;
      const int q = sseg ^ (row & 7);
      gload_lds16(Ag + (size_t)row * GKS + kt * 64 + q * 8, As + i * 8192 + wid * 1024);
      gload_lds16(Bg + (size_t)row * GKS + kt * 64 + q * 8, Bs + i * 8192 + wid * 1024);
    }
  };

  f32x4 acc[8][4] = {};
  const int nt_k = kchunk / 64;
  stage(0, 0);
  for (int kt = 0; kt < nt_k; ++kt) {
    const int p = kt & 1;
    if (kt + 1 < nt_k) {
      stage(kt + 1, p ^ 1);
      asm volatile("s_waitcnt vmcnt(8)" ::: "memory");
    } else {
      asm volatile("s_waitcnt vmcnt(0)" ::: "memory");
    }
    __builtin_amdgcn_s_barrier();
    const char* As = lds + p * 65536;
    const char* Bs = lds + p * 65536 + 32768;
    bf16x8 bfrag[4][2];
#pragma unroll
    for (int q = 0; q < 4; ++q) {
      if (q == 0) {
#pragma unroll
        for (int fj = 0; fj < 4; ++fj)
#pragma unroll
          for (int kk = 0; kk < 2; ++kk) {
            const int row = wn * 64 + fj * 16 + fr;
            const int seg = (kk * 4 + fg) ^ (row & 7);
            bfrag[fj][kk] = *(const bf16x8*)(Bs + row * 128 + seg * 16);
          }
      }
      bf16x8 af[2][2];
#pragma unroll
      for (int fil = 0; fil < 2; ++fil)
#pragma unroll
        for (int kk = 0; kk < 2; ++kk) {
          const int row = wm * 128 + (q * 2 + fil) * 16 + fr;
          const int seg = (kk * 4 + fg) ^ (row & 7);
          af[fil][kk] = *(const bf16x8*)(As + row * 128 + seg * 16);
        }
      __builtin_amdgcn_s_barrier();
      asm volatile("s_waitcnt lgkmcnt(0)" ::: "memory");
      __builtin_amdgcn_sched_barrier(0);
      __builtin_amdgcn_s_setprio(1);
#pragma unroll
      for (int fil = 0; fil < 2; ++fil)
#pragma unroll
        for (int fj = 0; fj < 4; ++fj)
#pragma unroll
          for (int kk = 0; kk < 2; ++kk)
            acc[q * 2 + fil][fj] = __builtin_amdgcn_mfma_f32_16x16x32_bf16(
                bfrag[fj][kk], af[fil][kk], acc[q * 2 + fil][fj], 0, 0, 0);
      __builtin_amdgcn_s_setprio(0);
      __builtin_amdgcn_s_barrier();
    }
  }

  float* Pp = P + (size_t)s * Mm * Dd;
  const int fq = lane >> 4;
#pragma unroll
  for (int fi = 0; fi < 8; ++fi) {
    const size_t m = (size_t)mt * 256 + wm * 128 + fi * 16 + fr;
    float* pp = Pp + m * Dd + nt * 256 + wn * 64 + fq * 4;
#pragma unroll
    for (int fj = 0; fj < 4; ++fj) *(f32x4*)(pp + fj * 16) = acc[fi][fj];
  }
}

// ---------------- reduce partials + bias ------------------------------------
__global__ __launch_bounds__(256) void reduce_bias(
    const float* __restrict__ P, const float* __restrict__ wts,
    const float* __restrict__ b2, float* __restrict__ out, int S) {
  const int n4 = Mm * Dd / 4;
  int i = blockIdx.x * 256 + threadIdx.x;
  if (i >= n4) return;
  const int m = i / (Dd / 4);
  const int d0 = (i % (Dd / 4)) * 4;
  float4 a = ((const float4*)P)[i];
  for (int s = 1; s < S; ++s) {
    float4 p = ((const float4*)P)[(size_t)s * n4 + i];
    a.x += p.x; a.y += p.y; a.z += p.z; a.w += p.w;
  }
  const float* wr = wts + (size_t)m * Ee;
#pragma unroll
  for (int e = 0; e < Ee; ++e) {
    const float w = wr[e];
    float4 b = *(const float4*)(b2 + e * Dd + d0);
    a.x += w * b.x; a.y += w * b.y; a.z += w * b.z; a.w += w * b.w;
  }
  ((float4*)out)[i] = a;
}

// ============ fallback: 128^2 m97-structure path (R3 proven) ================
template <int ARS, int BRS>
DEV void gemm_core(const bf16* __restrict__ Ag, const bf16* __restrict__ Bg,
                   int ksteps, f32x4 (&acc)[4][4], bf16* As, bf16* Bs) {
  const int t = threadIdx.x;
  const int lane = t & 63;
  const int w = t >> 6;
  const int srow = t >> 3;
  const int sseg = t & 7;
  const int wr = w >> 1, wc = w & 1;
  const int fr = lane & 15;
  const int fg = lane >> 4;
  for (int s = 0; s < ksteps; ++s) {
    __syncthreads();
#pragma unroll
    for (int i = 0; i < 4; ++i) {
      const int row = i * 32 + srow;
      const int q = sseg ^ (row & 7);
      gload_lds16(Ag + (size_t)row * ARS + s * 64 + q * 8,
                  (char*)As + i * 4096 + w * 1024);
      gload_lds16(Bg + (size_t)row * BRS + s * 64 + q * 8,
                  (char*)Bs + i * 4096 + w * 1024);
    }
    __syncthreads();
#pragma unroll
    for (int kk = 0; kk < 2; ++kk) {
      bf16x8 af[4], bfr[4];
#pragma unroll
      for (int mi = 0; mi < 4; ++mi) {
        const int row = wr * 64 + mi * 16 + fr;
        const int q = (kk * 4 + fg) ^ (row & 7);
        af[mi] = *(const bf16x8*)((const char*)As + row * 128 + q * 16);
      }
#pragma unroll
      for (int ni = 0; ni < 4; ++ni) {
        const int row = wc * 64 + ni * 16 + fr;
        const int q = (kk * 4 + fg) ^ (row & 7);
        bfr[ni] = *(const bf16x8*)((const char*)Bs + row * 128 + q * 16);
      }
#pragma unroll
      for (int mi = 0; mi < 4; ++mi)
#pragma unroll
        for (int ni = 0; ni < 4; ++ni)
          acc[mi][ni] = __builtin_amdgcn_mfma_f32_16x16x32_bf16(
              af[mi], bfr[ni], acc[mi][ni], 0, 0, 0);
    }
  }
}

__global__ __launch_bounds__(256) void ffn_stage1_t(
    const bf16* __restrict__ xb, const bf16* __restrict__ w1t,
    const float* __restrict__ b1, const float* __restrict__ wts,
    bf16* __restrict__ G) {
  __shared__ __align__(16) bf16 As[128 * 64];
  __shared__ __align__(16) bf16 Bs[128 * 64];
  __shared__ float b1s[128];
  __shared__ float wls[128];
  const int mt = blockIdx.x, ht = blockIdx.y, e = blockIdx.z;
  const int t = threadIdx.x;
  if (t < 128) b1s[t] = b1[e * Hh + ht * 128 + t];
  else wls[t - 128] = wts[((size_t)mt * 128 + (t - 128)) * Ee + e];
  f32x4 acc[4][4] = {};
  const bf16* Ag = xb + (size_t)mt * 128 * Dd;
  const bf16* Bg = w1t + ((size_t)e * Hh + (size_t)ht * 128) * Dd;
  gemm_core<Dd, Dd>(Ag, Bg, Dd / 64, acc, As, Bs);
  const int lane = t & 63, w = t >> 6;
  const int wr = w >> 1, wc = w & 1, fr = lane & 15, fq = lane >> 4;
  float bcol[4];
#pragma unroll
  for (int ni = 0; ni < 4; ++ni) bcol[ni] = b1s[wc * 64 + ni * 16 + fr];
  bf16* gp = G + ((size_t)mt * 128 + wr * 64 + fq * 4) * GKS
               + (size_t)e * Hh + ht * 128 + wc * 64 + fr;
#pragma unroll
  for (int mi = 0; mi < 4; ++mi)
#pragma unroll
    for (int r = 0; r < 4; ++r) {
      const float wgt = wls[wr * 64 + mi * 16 + fq * 4 + r];
#pragma unroll
      for (int ni = 0; ni < 4; ++ni) {
        float v = acc[mi][ni][r] + bcol[ni];
        gp[(size_t)(mi * 16 + r) * GKS + ni * 16] = (bf16)(gelu_fast(v) * wgt);
      }
    }
}

__global__ __launch_bounds__(256) void ffn_stage2_partial(
    const bf16* __restrict__ G, const bf16* __restrict__ w2t,
    float* __restrict__ P, int kchunk) {
  __shared__ __align__(16) bf16 As[128 * 64];
  __shared__ __align__(16) bf16 Bs[128 * 64];
  const int mt = blockIdx.x, nt = blockIdx.y, s = blockIdx.z;
  f32x4 acc[4][4] = {};
  const bf16* Ag = G + (size_t)mt * 128 * GKS + (size_t)s * kchunk;
  const bf16* Bg = w2t + (size_t)nt * 128 * GKS + (size_t)s * kchunk;
  gemm_core<GKS, GKS>(Ag, Bg, kchunk / 64, acc, As, Bs);
  float* Pp = P + (size_t)s * Mm * Dd;
  const int t = threadIdx.x;
  const int lane = t & 63, w = t >> 6;
  const int wr = w >> 1, wc = w & 1, fr = lane & 15, fq = lane >> 4;
#pragma unroll
  for (int mi = 0; mi < 4; ++mi)
#pragma unroll
    for (int r = 0; r < 4; ++r) {
      const size_t m = (size_t)mt * 128 + wr * 64 + mi * 16 + fq * 4 + r;
#pragma unroll
      for (int ni = 0; ni < 4; ++ni) {
        const int d = nt * 128 + wc * 64 + ni * 16 + fr;
        Pp[m * Dd + d] = acc[mi][ni][r];
      }
    }
}

// ---------------- launch ----------------------------------------------------
extern "C" void kernel_launch(void* const* d_in, const int* in_sizes, int n_in,
                              void* d_out, int out_size, void* d_ws, size_t ws_size,
                              hipStream_t stream) {
  const float* x   = (const float*)d_in[0];
  const float* wts = (const float*)d_in[1];
  const float* w1  = (const float*)d_in[2];
  const float* b1  = (const float*)d_in[3];
  const float* w2  = (const float*)d_in[4];
  const float* b2  = (const float*)d_in[5];
  float* out = (float*)d_out;

  char* ws = (char*)d_ws;
  size_t off = 0;
  bf16* xb  = (bf16*)(ws + off); off += (size_t)Mm * Dd * 2;
  bf16* w1t = (bf16*)(ws + off); off += (size_t)Ee * Hh * Dd * 2;
  bf16* w2t = (bf16*)(ws + off); off += (size_t)Dd * Ee * Hh * 2;

  const size_t gfull = (size_t)Mm * Ee * Hh * 2;  // 134 MB
  const size_t psz   = (size_t)Mm * Dd * 4;       // 16.8 MB

  cvt_x_kernel<<<(Mm * Dd / 4 + 255) / 256, 256, 0, stream>>>(x, xb, Mm * Dd / 4);
  transpose_cvt<<<dim3(Hh / 64, Dd / 64, Ee), 256, 0, stream>>>(
      w1, w1t, Dd, Hh, (size_t)Dd * Hh, (size_t)Hh * Dd, Dd);
  transpose_cvt<<<dim3(Dd / 64, Hh / 64, Ee), 256, 0, stream>>>(
      w2, w2t, Hh, Dd, (size_t)Hh * Dd, (size_t)Hh, Ee * Hh);

  if (ws_size >= off + gfull + 4 * psz) {
    // main path: persistent stage1 (1 round) + 256^2 stage2 split-K S=4
    bf16* G = (bf16*)(ws + off);
    float* P = (float*)(ws + off + gfull);
    ffn_stage1_256<<<dim3(Mm / 256, Ee), 512, 0, stream>>>(
        xb, w1t, b1, wts, G);
    ffn_stage2_256<<<dim3(Mm / 256, Dd / 256, 4), 512, 0, stream>>>(
        G, w2t, P, GKS / 4);
    reduce_bias<<<(Mm * Dd / 4 + 255) / 256, 256, 0, stream>>>(P, wts, b2, out, 4);
  } else if (ws_size >= off + gfull + 2 * psz) {
    // fallback: 128^2 split-K S=2 (R3 proven)
    bf16* G = (bf16*)(ws + off);
    float* P = (float*)(ws + off + gfull);
    ffn_stage1_t<<<dim3(Mm / 128, Hh / 128, Ee), 256, 0, stream>>>(
        xb, w1t, b1, wts, G);
    ffn_stage2_partial<<<dim3(Mm / 128, Dd / 128, 2), 256, 0, stream>>>(
        G, w2t, P, GKS / 2);
    reduce_bias<<<(Mm * Dd / 4 + 255) / 256, 256, 0, stream>>>(P, wts, b2, out, 2);
  }
}

// Round 8
// 212.025 us; speedup vs baseline: 1.0916x; 1.0479x over previous
//
#include <hip/hip_runtime.h>
#include <hip/hip_bf16.h>

#define DEV __device__ __forceinline__

typedef __bf16 bf16;
typedef __bf16 bf16x4 __attribute__((ext_vector_type(4)));
typedef __bf16 bf16x8 __attribute__((ext_vector_type(8)));
typedef float f32x4 __attribute__((ext_vector_type(4)));

static constexpr int Bb = 4, Ll = 2048, Dd = 512, Ee = 8, Hh = 1024;
static constexpr int Mm = Bb * Ll;  // 8192 tokens
static constexpr int GKS = Ee * Hh; // 8192, G row stride

// ---------------- async global->LDS (16B per lane, wave-uniform LDS base) ---
DEV void gload_lds16(const void* g, void* l) {
  __builtin_amdgcn_global_load_lds(
      (const __attribute__((address_space(1))) unsigned int*)g,
      (__attribute__((address_space(3))) unsigned int*)l, 16, 0, 0);
}

// fast exact-enough gelu: tanh form, g = h - h/(exp(2y)+1)
DEV float gelu_fast(float h) {
  const float k = 0.7978845608028654f * 2.0f * 1.4426950408889634f;
  float h2 = h * h;
  float y = h * (k + (0.044715f * k) * h2);
  float t = exp2f(y);
  return h - h * __frcp_rn(t + 1.0f);
}

// ---------------- elementwise f32 -> bf16 -----------------------------------
__global__ void cvt_x_kernel(const float* __restrict__ in, bf16* __restrict__ out, int n4) {
  int i = blockIdx.x * blockDim.x + threadIdx.x;
  if (i < n4) {
    float4 v = ((const float4*)in)[i];
    bf16x4 o = {(bf16)v.x, (bf16)v.y, (bf16)v.z, (bf16)v.w};
    ((bf16x4*)out)[i] = o;
  }
}

// ---------------- tiled transpose + convert ---------------------------------
__global__ void transpose_cvt(const float* __restrict__ in, bf16* __restrict__ out,
                              int R, int C, size_t in_es, size_t out_es, int out_rs) {
  __shared__ float tile[64][65];
  const int e = blockIdx.z;
  const float* ip = in + (size_t)e * in_es;
  bf16* op = out + (size_t)e * out_es;
  const int r0 = blockIdx.y * 64, c0 = blockIdx.x * 64;
  const int tc = threadIdx.x & 63, tr = threadIdx.x >> 6;
#pragma unroll
  for (int i = 0; i < 16; ++i) {
    const int r = tr + i * 4;
    tile[r][tc] = ip[(size_t)(r0 + r) * C + c0 + tc];
  }
  __syncthreads();
  const int wr = threadIdx.x & 63, wc0 = threadIdx.x >> 6;
#pragma unroll
  for (int i = 0; i < 16; ++i) {
    const int c = wc0 + i * 4;
    op[(size_t)(c0 + c) * out_rs + r0 + wr] = (bf16)tile[wr][c];
  }
}

// ---------------- barrier-light compute for one 256x256x64 K-tile -----------
// No internal barriers: frag ds_reads software-pipelined (phase q+1 issued
// before phase q's MFMAs); compiler inserts counted lgkmcnt for reg deps.
DEV void compute_tile(const char* As, const char* Bs, f32x4 (&acc)[8][4],
                      int wm, int wn, int fr, int fg) {
  bf16x8 bfrag[4][2];
#pragma unroll
  for (int fj = 0; fj < 4; ++fj)
#pragma unroll
    for (int kk = 0; kk < 2; ++kk) {
      const int row = wn * 64 + fj * 16 + fr;
      const int seg = (kk * 4 + fg) ^ (row & 7);
      bfrag[fj][kk] = *(const bf16x8*)(Bs + row * 128 + seg * 16);
    }
  bf16x8 af[2][2][2];  // [phase parity][fil][kk]
#pragma unroll
  for (int fil = 0; fil < 2; ++fil)
#pragma unroll
    for (int kk = 0; kk < 2; ++kk) {
      const int row = wm * 128 + fil * 16 + fr;
      const int seg = (kk * 4 + fg) ^ (row & 7);
      af[0][fil][kk] = *(const bf16x8*)(As + row * 128 + seg * 16);
    }
#pragma unroll
  for (int q = 0; q < 4; ++q) {
    if (q < 3) {
#pragma unroll
      for (int fil = 0; fil < 2; ++fil)
#pragma unroll
        for (int kk = 0; kk < 2; ++kk) {
          const int row = wm * 128 + ((q + 1) * 2 + fil) * 16 + fr;
          const int seg = (kk * 4 + fg) ^ (row & 7);
          af[(q + 1) & 1][fil][kk] = *(const bf16x8*)(As + row * 128 + seg * 16);
        }
    }
    __builtin_amdgcn_s_setprio(1);
#pragma unroll
    for (int fil = 0; fil < 2; ++fil)
#pragma unroll
      for (int fj = 0; fj < 4; ++fj)
#pragma unroll
        for (int kk = 0; kk < 2; ++kk)
          acc[q * 2 + fil][fj] = __builtin_amdgcn_mfma_f32_16x16x32_bf16(
              bfrag[fj][kk], af[q & 1][fil][kk], acc[q * 2 + fil][fj], 0, 0, 0);
    __builtin_amdgcn_s_setprio(0);
  }
}

// ---------------- stage 1: persistent over ht2, 2 barriers/K-tile -----------
__global__ __launch_bounds__(512, 2) void ffn_stage1_256(
    const bf16* __restrict__ xb, const bf16* __restrict__ w1t,
    const float* __restrict__ b1, const float* __restrict__ wts,
    bf16* __restrict__ G) {
  __shared__ __align__(16) char lds[131072];
  __shared__ float b1s[1024];
  __shared__ float wls[256];
  const int mt = blockIdx.x, e = blockIdx.y;
  const int t = threadIdx.x;
  b1s[t] = b1[e * Hh + t];
  b1s[512 + t] = b1[e * Hh + 512 + t];
  if (t < 256) wls[t] = wts[((size_t)mt * 256 + t) * Ee + e];

  const int lane = t & 63;
  const int wid = t >> 6;
  const int wm = wid >> 2, wn = wid & 3;
  const int fr = lane & 15, fg = lane >> 4, fq = lane >> 4;
  const int srow = t >> 3;
  const int sseg = t & 7;

  const bf16* Ag = xb + (size_t)mt * 256 * Dd;
  const bf16* Bg0 = w1t + (size_t)e * Hh * Dd;

  auto stage = [&](int it, int p) {
    const int ht2n = it >> 3, ktn = it & 7;
    const bf16* Bg = Bg0 + (size_t)ht2n * 256 * Dd;
    char* As = lds + p * 65536;
    char* Bs = lds + p * 65536 + 32768;
#pragma unroll
    for (int i = 0; i < 4; ++i) {
      const int row = i * 64 + srow;
      const int q = sseg ^ (row & 7);
      gload_lds16(Ag + (size_t)row * Dd + ktn * 64 + q * 8, As + i * 8192 + wid * 1024);
      gload_lds16(Bg + (size_t)row * Dd + ktn * 64 + q * 8, Bs + i * 8192 + wid * 1024);
    }
  };

  f32x4 acc[8][4] = {};
  stage(0, 0);
  for (int it = 0; it < 32; ++it) {
    const int p = it & 1;
    if (it + 1 < 32) {
      stage(it + 1, p ^ 1);  // safe: all waves passed prev trailing barrier
      asm volatile("s_waitcnt vmcnt(8)" ::: "memory");  // own loads for it landed
    } else {
      asm volatile("s_waitcnt vmcnt(0)" ::: "memory");
    }
    __builtin_amdgcn_s_barrier();  // everyone's loads for it landed

    compute_tile(lds + p * 65536, lds + p * 65536 + 32768, acc, wm, wn, fr, fg);

    __builtin_amdgcn_s_barrier();  // all waves done reading buffer p

    if ((it & 7) == 7) {
      const int ht2 = it >> 3;
      float b1v[4][4];
#pragma unroll
      for (int fj = 0; fj < 4; ++fj)
#pragma unroll
        for (int r = 0; r < 4; ++r)
          b1v[fj][r] = b1s[ht2 * 256 + wn * 64 + fj * 16 + fq * 4 + r];
#pragma unroll
      for (int fi = 0; fi < 8; ++fi) {
        const int m = mt * 256 + wm * 128 + fi * 16 + fr;
        const float wgt = wls[wm * 128 + fi * 16 + fr];
        bf16* gp = G + (size_t)m * GKS + e * Hh + ht2 * 256 + wn * 64 + fq * 4;
#pragma unroll
        for (int fj = 0; fj < 4; ++fj) {
          bf16x4 o;
#pragma unroll
          for (int r = 0; r < 4; ++r) {
            float v = acc[fi][fj][r] + b1v[fj][r];
            o[r] = (bf16)(gelu_fast(v) * wgt);
          }
          *(bf16x4*)(gp + fj * 16) = o;
        }
#pragma unroll
        for (int fj = 0; fj < 4; ++fj) acc[fi][fj] = (f32x4){0.f, 0.f, 0.f, 0.f};
      }
    }
  }
}

// ---------------- stage 2 (256^2) split-K partial, 2 barriers/K-tile --------
__global__ __launch_bounds__(512, 2) void ffn_stage2_256(
    const bf16* __restrict__ G, const bf16* __restrict__ w2t,
    float* __restrict__ P, int kchunk) {
  __shared__ __align__(16) char lds[131072];
  const int mt = blockIdx.x, nt = blockIdx.y, s = blockIdx.z;
  const int t = threadIdx.x;
  const int lane = t & 63;
  const int wid = t >> 6;
  const int wm = wid >> 2, wn = wid & 3;
  const int fr = lane & 15, fg = lane >> 4;
  const int srow = t >> 3;
  const int sseg = t & 7;

  const bf16* Ag = G + (size_t)mt * 256 * GKS + (size_t)s * kchunk;
  const bf16* Bg = w2t + (size_t)nt * 256 * GKS + (size_t)s * kchunk;

  auto stage = [&](int kt, int p) {
    char* As = lds + p * 65536;
    char* Bs = lds + p * 65536 + 32768;
#pragma unroll
    for (int i = 0; i < 4; ++i) {
      const int row = i * 64 + srow;
      const int q = sseg ^ (row & 7);
      gload_lds16(Ag + (size_t)row * GKS + kt * 64 + q * 8, As + i * 8192 + wid * 1024);
      gload_lds16(Bg + (size_t)row * GKS + kt * 64 + q * 8, Bs + i * 8192 + wid * 1024);
    }
  };

  f32x4 acc[8][4] = {};
  const int nt_k = kchunk / 64;
  stage(0, 0);
  for (int kt = 0; kt < nt_k; ++kt) {
    const int p = kt & 1;
    if (kt + 1 < nt_k) {
      stage(kt + 1, p ^ 1);
      asm volatile("s_waitcnt vmcnt(8)" ::: "memory");
    } else {
      asm volatile("s_waitcnt vmcnt(0)" ::: "memory");
    }
    __builtin_amdgcn_s_barrier();

    compute_tile(lds + p * 65536, lds + p * 65536 + 32768, acc, wm, wn, fr, fg);

    __builtin_amdgcn_s_barrier();
  }

  float* Pp = P + (size_t)s * Mm * Dd;
  const int fq = lane >> 4;
#pragma unroll
  for (int fi = 0; fi < 8; ++fi) {
    const size_t m = (size_t)mt * 256 + wm * 128 + fi * 16 + fr;
    float* pp = Pp + m * Dd + nt * 256 + wn * 64 + fq * 4;
#pragma unroll
    for (int fj = 0; fj < 4; ++fj) *(f32x4*)(pp + fj * 16) = acc[fi][fj];
  }
}

// ---------------- reduce partials + bias ------------------------------------
__global__ __launch_bounds__(256) void reduce_bias(
    const float* __restrict__ P, const float* __restrict__ wts,
    const float* __restrict__ b2, float* __restrict__ out, int S) {
  const int n4 = Mm * Dd / 4;
  int i = blockIdx.x * 256 + threadIdx.x;
  if (i >= n4) return;
  const int m = i / (Dd / 4);
  const int d0 = (i % (Dd / 4)) * 4;
  float4 a = ((const float4*)P)[i];
  for (int s = 1; s < S; ++s) {
    float4 p = ((const float4*)P)[(size_t)s * n4 + i];
    a.x += p.x; a.y += p.y; a.z += p.z; a.w += p.w;
  }
  const float* wr = wts + (size_t)m * Ee;
#pragma unroll
  for (int e = 0; e < Ee; ++e) {
    const float w = wr[e];
    float4 b = *(const float4*)(b2 + e * Dd + d0);
    a.x += w * b.x; a.y += w * b.y; a.z += w * b.z; a.w += w * b.w;
  }
  ((float4*)out)[i] = a;
}

// ============ fallback: 128^2 m97-structure path (R3 proven) ================
template <int ARS, int BRS>
DEV void gemm_core(const bf16* __restrict__ Ag, const bf16* __restrict__ Bg,
                   int ksteps, f32x4 (&acc)[4][4], bf16* As, bf16* Bs) {
  const int t = threadIdx.x;
  const int lane = t & 63;
  const int w = t >> 6;
  const int srow = t >> 3;
  const int sseg = t & 7;
  const int wr = w >> 1, wc = w & 1;
  const int fr = lane & 15;
  const int fg = lane >> 4;
  for (int s = 0; s < ksteps; ++s) {
    __syncthreads();
#pragma unroll
    for (int i = 0; i < 4; ++i) {
      const int row = i * 32 + srow;
      const int q = sseg ^ (row & 7);
      gload_lds16(Ag + (size_t)row * ARS + s * 64 + q * 8,
                  (char*)As + i * 4096 + w * 1024);
      gload_lds16(Bg + (size_t)row * BRS + s * 64 + q * 8,
                  (char*)Bs + i * 4096 + w * 1024);
    }
    __syncthreads();
#pragma unroll
    for (int kk = 0; kk < 2; ++kk) {
      bf16x8 af[4], bfr[4];
#pragma unroll
      for (int mi = 0; mi < 4; ++mi) {
        const int row = wr * 64 + mi * 16 + fr;
        const int q = (kk * 4 + fg) ^ (row & 7);
        af[mi] = *(const bf16x8*)((const char*)As + row * 128 + q * 16);
      }
#pragma unroll
      for (int ni = 0; ni < 4; ++ni) {
        const int row = wc * 64 + ni * 16 + fr;
        const int q = (kk * 4 + fg) ^ (row & 7);
        bfr[ni] = *(const bf16x8*)((const char*)Bs + row * 128 + q * 16);
      }
#pragma unroll
      for (int mi = 0; mi < 4; ++mi)
#pragma unroll
        for (int ni = 0; ni < 4; ++ni)
          acc[mi][ni] = __builtin_amdgcn_mfma_f32_16x16x32_bf16(
              af[mi], bfr[ni], acc[mi][ni], 0, 0, 0);
    }
  }
}

__global__ __launch_bounds__(256) void ffn_stage1_t(
    const bf16* __restrict__ xb, const bf16* __restrict__ w1t,
    const float* __restrict__ b1, const float* __restrict__ wts,
    bf16* __restrict__ G) {
  __shared__ __align__(16) bf16 As[128 * 64];
  __shared__ __align__(16) bf16 Bs[128 * 64];
  __shared__ float b1s[128];
  __shared__ float wls[128];
  const int mt = blockIdx.x, ht = blockIdx.y, e = blockIdx.z;
  const int t = threadIdx.x;
  if (t < 128) b1s[t] = b1[e * Hh + ht * 128 + t];
  else wls[t - 128] = wts[((size_t)mt * 128 + (t - 128)) * Ee + e];
  f32x4 acc[4][4] = {};
  const bf16* Ag = xb + (size_t)mt * 128 * Dd;
  const bf16* Bg = w1t + ((size_t)e * Hh + (size_t)ht * 128) * Dd;
  gemm_core<Dd, Dd>(Ag, Bg, Dd / 64, acc, As, Bs);
  const int lane = t & 63, w = t >> 6;
  const int wr = w >> 1, wc = w & 1, fr = lane & 15, fq = lane >> 4;
  float bcol[4];
#pragma unroll
  for (int ni = 0; ni < 4; ++ni) bcol[ni] = b1s[wc * 64 + ni * 16 + fr];
  bf16* gp = G + ((size_t)mt * 128 + wr * 64 + fq * 4) * GKS
               + (size_t)e * Hh + ht * 128 + wc * 64 + fr;
#pragma unroll
  for (int mi = 0; mi < 4; ++mi)
#pragma unroll
    for (int r = 0; r < 4; ++r) {
      const float wgt = wls[wr * 64 + mi * 16 + fq * 4 + r];
#pragma unroll
      for (int ni = 0; ni < 4; ++ni) {
        float v = acc[mi][ni][r] + bcol[ni];
        gp[(size_t)(mi * 16 + r) * GKS + ni * 16] = (bf16)(gelu_fast(v) * wgt);
      }
    }
}

__global__ __launch_bounds__(256) void ffn_stage2_partial(
    const bf16* __restrict__ G, const bf16* __restrict__ w2t,
    float* __restrict__ P, int kchunk) {
  __shared__ __align__(16) bf16 As[128 * 64];
  __shared__ __align__(16) bf16 Bs[128 * 64];
  const int mt = blockIdx.x, nt = blockIdx.y, s = blockIdx.z;
  f32x4 acc[4][4] = {};
  const bf16* Ag = G + (size_t)mt * 128 * GKS + (size_t)s * kchunk;
  const bf16* Bg = w2t + (size_t)nt * 128 * GKS + (size_t)s * kchunk;
  gemm_core<GKS, GKS>(Ag, Bg, kchunk / 64, acc, As, Bs);
  float* Pp = P + (size_t)s * Mm * Dd;
  const int t = threadIdx.x;
  const int lane = t & 63, w = t >> 6;
  const int wr = w >> 1, wc = w & 1, fr = lane & 15, fq = lane >> 4;
#pragma unroll
  for (int mi = 0; mi < 4; ++mi)
#pragma unroll
    for (int r = 0; r < 4; ++r) {
      const size_t m = (size_t)mt * 128 + wr * 64 + mi * 16 + fq * 4 + r;
#pragma unroll
      for (int ni = 0; ni < 4; ++ni) {
        const int d = nt * 128 + wc * 64 + ni * 16 + fr;
        Pp[m * Dd + d] = acc[mi][ni][r];
      }
    }
}

// ---------------- launch ----------------------------------------------------
extern "C" void kernel_launch(void* const* d_in, const int* in_sizes, int n_in,
                              void* d_out, int out_size, void* d_ws, size_t ws_size,
                              hipStream_t stream) {
  const float* x   = (const float*)d_in[0];
  const float* wts = (const float*)d_in[1];
  const float* w1  = (const float*)d_in[2];
  const float* b1  = (const float*)d_in[3];
  const float* w2  = (const float*)d_in[4];
  const float* b2  = (const float*)d_in[5];
  float* out = (float*)d_out;

  char* ws = (char*)d_ws;
  size_t off = 0;
  bf16* xb  = (bf16*)(ws + off); off += (size_t)Mm * Dd * 2;
  bf16* w1t = (bf16*)(ws + off); off += (size_t)Ee * Hh * Dd * 2;
  bf16* w2t = (bf16*)(ws + off); off += (size_t)Dd * Ee * Hh * 2;

  const size_t gfull = (size_t)Mm * Ee * Hh * 2;  // 134 MB
  const size_t psz   = (size_t)Mm * Dd * 4;       // 16.8 MB

  cvt_x_kernel<<<(Mm * Dd / 4 + 255) / 256, 256, 0, stream>>>(x, xb, Mm * Dd / 4);
  transpose_cvt<<<dim3(Hh / 64, Dd / 64, Ee), 256, 0, stream>>>(
      w1, w1t, Dd, Hh, (size_t)Dd * Hh, (size_t)Hh * Dd, Dd);
  transpose_cvt<<<dim3(Dd / 64, Hh / 64, Ee), 256, 0, stream>>>(
      w2, w2t, Hh, Dd, (size_t)Hh * Dd, (size_t)Hh, Ee * Hh);

  if (ws_size >= off + gfull + 4 * psz) {
    // main path: barrier-light persistent stage1 + 256^2 stage2 split-K S=4
    bf16* G = (bf16*)(ws + off);
    float* P = (float*)(ws + off + gfull);
    ffn_stage1_256<<<dim3(Mm / 256, Ee), 512, 0, stream>>>(
        xb, w1t, b1, wts, G);
    ffn_stage2_256<<<dim3(Mm / 256, Dd / 256, 4), 512, 0, stream>>>(
        G, w2t, P, GKS / 4);
    reduce_bias<<<(Mm * Dd / 4 + 255) / 256, 256, 0, stream>>>(P, wts, b2, out, 4);
  } else if (ws_size >= off + gfull + 2 * psz) {
    // fallback: 128^2 split-K S=2 (R3 proven)
    bf16* G = (bf16*)(ws + off);
    float* P = (float*)(ws + off + gfull);
    ffn_stage1_t<<<dim3(Mm / 128, Hh / 128, Ee), 256, 0, stream>>>(
        xb, w1t, b1, wts, G);
    ffn_stage2_partial<<<dim3(Mm / 128, Dd / 128, 2), 256, 0, stream>>>(
        G, w2t, P, GKS / 2);
    reduce_bias<<<(Mm * Dd / 4 + 255) / 256, 256, 0, stream>>>(P, wts, b2, out, 2);
  }
}